// Round 5
// baseline (316.956 us; speedup 1.0000x reference)
//
#include <hip/hip_runtime.h>
#include <math.h>

// Problem constants (x: [2048, 2048, 3, 3] f32, bits=8)
// channel stride = h*w = 9 floats; group-block = 8 channels * 9 = 72
// consecutive floats = 18 float4; n = 37,748,736 = 524,288 group-blocks
// = 2048 blocks x 256 rows exactly.
#define HW        9
#define GROUP     8
#define KEEP      4
#define DELTA     127.0f
#define INV_DELTA (1.0f / 127.0f)
#define ROW_F4    18          // float4 per group-block
#define ROW_PAD   19          // padded row stride in float4 (76 floats; 76%32=12 -> conflict-free b128)
#define ROWS      256         // group-blocks per block

// ---------------- Kernel 1: global max|x| ----------------
__global__ void maxabs_kernel(const float4* __restrict__ x, unsigned* __restrict__ ws, int n4) {
    __shared__ float red[4];
    float m = 0.0f;
    int stride = gridDim.x * blockDim.x;
    #pragma unroll 4
    for (int i = blockIdx.x * blockDim.x + threadIdx.x; i < n4; i += stride) {
        float4 v = x[i];
        m = fmaxf(m, fmaxf(fmaxf(fabsf(v.x), fabsf(v.y)),
                           fmaxf(fabsf(v.z), fabsf(v.w))));
    }
    #pragma unroll
    for (int off = 32; off > 0; off >>= 1)
        m = fmaxf(m, __shfl_down(m, off, 64));
    int wave = threadIdx.x >> 6;
    if ((threadIdx.x & 63) == 0) red[wave] = m;
    __syncthreads();
    if (threadIdx.x == 0) {
        float b = fmaxf(fmaxf(red[0], red[1]), fmaxf(red[2], red[3]));
        atomicMax(ws, __float_as_uint(b));   // |x|>=0: float bit order == uint order
    }
}

// Cold bit-exact reference path (identical to the round-1 passing kernel):
// t = (float)tanh(double x); y = t/M (f32 div); z = y*127; rint.
__device__ __attribute__((noinline)) float ref_rz(float xx, float M) {
    float td = (float)tanh((double)xx);
    float y  = td / M;
    return rintf(y * DELTA);
}

// Fast f32 tanh. Poly (|x|<=0.5): Taylor odd series through x^11,
// rel err <= ~2.5e-7. Exp form else: (E-1)/(E+1) with native exp + NR rcp,
// rel err <= ~1e-6.
__device__ __forceinline__ float fast_tanh(float x) {
    float ax  = fabsf(x);
    float axc = fminf(ax, 10.0f);
    float E   = __expf(2.0f * axc);
    float num = E - 1.0f;
    float den = E + 1.0f;
    float r0  = __builtin_amdgcn_rcpf(den);
    float r   = r0 * fmaf(-den, r0, 2.0f);      // one Newton step
    float tl  = copysignf(num * r, x);
    float s = x * x;
    float p = fmaf(s, 0.0035921280f, -0.0088632358f);  // 21844/6081075, -1382/155925
    p = fmaf(s, p, 0.021869488f);                       // 62/2835
    p = fmaf(s, p, -0.053968254f);                      // -17/315
    p = fmaf(s, p, 0.13333334f);                        // 2/15
    p = fmaf(s, p, -0.33333334f);                       // -1/3
    float ts = fmaf(x * s, p, x);
    return (ax <= 0.5f) ? ts : tl;
}

// ---------------- Kernel 2: quantize + group top-4 mask ----------------
// Block = 256 threads = 256 group-blocks (73728 B), staged through a padded
// LDS tile so ALL global traffic is lane-coalesced float4:
//   A) coalesced loads -> LDS (scatter to padded rows)
//   B) thread t reads its own row t (b128, conflict-free)  [no barrier vs C]
//   C) thread t writes results to row t
//   D) coalesced LDS -> global stores
__global__ void quant_kernel(const float4* __restrict__ x,
                             float4* __restrict__ out,
                             const unsigned* __restrict__ ws) {
    __shared__ float4 tile[ROWS * ROW_PAD];   // 77824 B
    __shared__ float sM, sC;
    if (threadIdx.x == 0) {
        // M = max|tanh(x)| = tanh(max|x|) (tanh odd+monotone; RNE symmetric)
        float mm = (float)tanh((double)__uint_as_float(*ws));
        sM = mm;
        sC = (float)(127.0 / (double)mm);
    }

    int t = threadIdx.x;
    size_t blk_f4 = (size_t)blockIdx.x * (ROWS * ROW_F4);

    // A: global -> LDS, coalesced
    #pragma unroll
    for (int k = 0; k < ROW_F4; ++k) {
        int L = k * ROWS + t;                // 0..4607, consecutive per lane
        float4 v = x[blk_f4 + L];
        int r = L / ROW_F4;
        int e = L - r * ROW_F4;
        tile[r * ROW_PAD + e] = v;
    }
    __syncthreads();
    float M = sM, C = sC;

    // B: own row -> registers
    float f[ROWS ? 72 : 0];
    #pragma unroll
    for (int e = 0; e < ROW_F4; ++e) {
        float4 v = tile[t * ROW_PAD + e];
        f[4 * e + 0] = v.x; f[4 * e + 1] = v.y;
        f[4 * e + 2] = v.z; f[4 * e + 3] = v.w;
    }

    // compute: 9 cells of (quantize + stable top-4 mask), in place
    #pragma unroll
    for (int hw = 0; hw < HW; ++hw) {
        float v8[GROUP], a8[GROUP];
        #pragma unroll
        for (int j = 0; j < GROUP; ++j) {
            float xx = f[j * HW + hw];
            float t1 = fast_tanh(xx);
            float z  = t1 * C;
            float rz = rintf(z);                 // numpy round: half-to-even
            float d  = 0.5f - fabsf(z - rz);     // distance to nearest half-int
            if (d < fmaf(2e-6f, fabsf(z), 5e-7f))
                rz = ref_rz(xx, M);              // cold, bit-exact chain
            v8[j] = rz;
            a8[j] = fabsf(rz);
        }
        // stable top-4: rank[j] = #{i beating j}; i<j beats iff a_i >= a_j
        int rank[GROUP] = {0, 0, 0, 0, 0, 0, 0, 0};
        #pragma unroll
        for (int i = 0; i < GROUP; ++i) {
            #pragma unroll
            for (int j = i + 1; j < GROUP; ++j) {
                bool ge = (a8[i] >= a8[j]);
                rank[j] += ge ? 1 : 0;
                rank[i] += ge ? 0 : 1;
            }
        }
        #pragma unroll
        for (int j = 0; j < GROUP; ++j) {
            f[j * HW + hw] = (rank[j] < KEEP) ? (v8[j] * INV_DELTA) : 0.0f;
        }
    }

    // C: results -> own row (only thread t touches row t; no barrier needed
    // between B and C)
    #pragma unroll
    for (int e = 0; e < ROW_F4; ++e) {
        float4 v;
        v.x = f[4 * e + 0]; v.y = f[4 * e + 1];
        v.z = f[4 * e + 2]; v.w = f[4 * e + 3];
        tile[t * ROW_PAD + e] = v;
    }
    __syncthreads();

    // D: LDS -> global, coalesced
    #pragma unroll
    for (int k = 0; k < ROW_F4; ++k) {
        int L = k * ROWS + t;
        int r = L / ROW_F4;
        int e = L - r * ROW_F4;
        out[blk_f4 + L] = tile[r * ROW_PAD + e];
    }
}

extern "C" void kernel_launch(void* const* d_in, const int* in_sizes, int n_in,
                              void* d_out, int out_size, void* d_ws, size_t ws_size,
                              hipStream_t stream) {
    const float* x = (const float*)d_in[0];
    float* out = (float*)d_out;
    unsigned* ws = (unsigned*)d_ws;

    int n = in_sizes[0];                 // 37,748,736
    int n4 = n / 4;
    int n_gb = n / 72;                   // 524,288 = 2048 * 256

    hipMemsetAsync(ws, 0, sizeof(unsigned), stream);

    maxabs_kernel<<<2048, 256, 0, stream>>>((const float4*)x, ws, n4);

    int blocks = n_gb / ROWS;            // 2048, exact
    quant_kernel<<<blocks, 256, 0, stream>>>((const float4*)x, (float4*)out, ws);
}